// Round 8
// baseline (137.699 us; speedup 1.0000x reference)
//
#include <hip/hip_runtime.h>

// out[m,n] = prod_d softplus(min(Zm,Ze)-max(zm,ze)) / softplus(Zm-zm)
//
// v9 = v7 with ONE isolated change: BN 64->32, per-thread tile 2x4->2x2,
// so LDS = 32KB(men) + 2x8KB(entity) = 48KB -> 3 blocks/CU = 24 waves
// (6/SIMD, 75% occ) vs the 2-block/4-wave ceiling every prior version sat
// at. Men staging, register-rden scheme, FD math: v7 VERBATIM.
//
// Why: VALU-busy TIME (VALUBusy*dur) is invariant ~62-65us across
// v1/v5/v6/v7/v8 (~30 cy/FD vs ~16-24 visible). Either (a) it's a hard
// single-issue-port floor (then dur_min ~= 62us) or (b) the counter sums
// main+trans pipes which can overlap ACROSS waves (floor ~= max pipe
// ~33-40us) and we never had enough waves/SIMD to see it. v9 is the
// experiment: 6 waves/SIMD. Falsifier: if dur is flat at ~75 with
// VALUBusy >=93%, model (a) holds -> v10 attacks per-FD issue count
// (polynomial log2; we have 4 orders of magnitude of error headroom).
//
// Math per unit (identical numerics to v1..v8, absmax 5.6e-17):
//   u = min(Em,Ee)*min(Im,Ie) = e^{min(Zm,Ze)-max(zm,ze)};
//   p *= log2(1+u); ln2^64 cancels between numerator and denominator;
//   final scale by full-row 1/prod_d log2(1+e^{Zm-zm}) (register-resident,
//   shfl_xor mul-reduced at staging).

#define BM 64
#define BN 32
#define DD 64

// one fused-dim unit: p *= log2(1 + minE*minI)  -- raw v_log_f32
#define FD(PIJ, EMc, IMc, EEc, IEc) \
    PIJ *= __builtin_amdgcn_logf(__builtin_fmaf(fminf(EMc, EEc), fminf(IMc, IEc), 1.0f));

__global__ __launch_bounds__(512, 6)
void ivr_kernel(const float* __restrict__ men, const float* __restrict__ en,
                float* __restrict__ out, int M, int N) {
    __shared__ __align__(16) float2 sMen[DD][BM];  // (e^{Zm}, e^{-zm}) [d][m] 32 KB
    __shared__ __align__(16) float  sEe[DD][BN];   // e^{Ze}   [d][n]           8 KB
    __shared__ __align__(16) float  sIe[DD][BN];   // e^{-ze}                   8 KB

    const int tx = threadIdx.x;
    const int m0 = blockIdx.y * BM;
    const int n0 = blockIdx.x * BN;

    // ---- men staging + in-register row denominator (v7 verbatim) ----
    // thread -> (row ml = tx>>3, 8-d chunk dcM = (tx&7)*8); 8 threads/row
    float rden;
    {
        const int ml  = tx >> 3;         // 0..63
        const int dcM = (tx & 7) * 8;    // this thread's 8 d's
        int mm = m0 + ml; if (mm >= M) mm = M - 1;
        const float* r = men + (size_t)mm * 128 + dcM;
        const float4 z0 = *reinterpret_cast<const float4*>(r);        // z (min)
        const float4 z1 = *reinterpret_cast<const float4*>(r + 4);
        const float4 Z0 = *reinterpret_cast<const float4*>(r + 64);   // Z (max)
        const float4 Z1 = *reinterpret_cast<const float4*>(r + 68);
        float Em, Im, prod;
#define MSTG(K, ZV, ZZ) { Em = __expf(ZZ); Im = __expf(-(ZV)); \
        sMen[dcM + (K)][ml] = make_float2(Em, Im); \
        prod *= __builtin_amdgcn_logf(__builtin_fmaf(Em, Im, 1.0f)); }
        Em = __expf(Z0.x); Im = __expf(-z0.x);
        sMen[dcM + 0][ml] = make_float2(Em, Im);
        prod = __builtin_amdgcn_logf(__builtin_fmaf(Em, Im, 1.0f));
        MSTG(1, z0.y, Z0.y) MSTG(2, z0.z, Z0.z) MSTG(3, z0.w, Z0.w)
        MSTG(4, z1.x, Z1.x) MSTG(5, z1.y, Z1.y) MSTG(6, z1.z, Z1.z) MSTG(7, z1.w, Z1.w)
#undef MSTG
        // multiply-reduce the 8 per-thread partials of this row
        prod *= __shfl_xor(prod, 1);
        prod *= __shfl_xor(prod, 2);
        prod *= __shfl_xor(prod, 4);
        rden = 1.0f / prod;              // full-row 1/denominator
    }
    // ---- entity staging: lane -> row (conflict-free LDS writes) ----
    // thread -> (row nl = tx&31, 4-d chunk dcE = (tx>>5)*4)
    {
        const int nl  = tx & 31;
        const int dcE = (tx >> 5) * 4;
        int nn = n0 + nl; if (nn >= N) nn = N - 1;
        const float* r = en + (size_t)nn * 128 + dcE;
        const float4 z0 = *reinterpret_cast<const float4*>(r);
        const float4 Z0 = *reinterpret_cast<const float4*>(r + 64);
        sEe[dcE + 0][nl] = __expf(Z0.x); sIe[dcE + 0][nl] = __expf(-z0.x);
        sEe[dcE + 1][nl] = __expf(Z0.y); sIe[dcE + 1][nl] = __expf(-z0.y);
        sEe[dcE + 2][nl] = __expf(Z0.z); sIe[dcE + 2][nl] = __expf(-z0.z);
        sEe[dcE + 3][nl] = __expf(Z0.w); sIe[dcE + 3][nl] = __expf(-z0.w);
    }
    __syncthreads();

    const int ni = (tx & 15) * 2;        // 16 n-groups of 2
    const int mi = (tx >> 4) * 2;        // 32 m-pairs

    // row-denominator pair for (mi, mi+1): this thread staged row ml=tx>>3
    // = mi + hib; partner lane tx^8 staged the sibling row. (v7 verbatim —
    // men mapping unchanged.)
    const float oden = __shfl_xor(rden, 8);
    const int hib = (tx >> 3) & 1;
    const float rd0 = hib ? oden : rden;
    const float rd1 = hib ? rden : oden;

    float p[2][2];
    p[0][0] = p[0][1] = p[1][0] = p[1][1] = 1.0f;

    // ---- compute: 2x2 units per d over all 64 d ----
    #pragma unroll 8
    for (int d = 0; d < DD; ++d) {
        const float4 mf  = *reinterpret_cast<const float4*>(&sMen[d][mi]);  // Em0,Im0,Em1,Im1
        const float2 Ee2 = *reinterpret_cast<const float2*>(&sEe[d][ni]);
        const float2 Ie2 = *reinterpret_cast<const float2*>(&sIe[d][ni]);
        FD(p[0][0], mf.x, mf.y, Ee2.x, Ie2.x)
        FD(p[0][1], mf.x, mf.y, Ee2.y, Ie2.y)
        FD(p[1][0], mf.z, mf.w, Ee2.x, Ie2.x)
        FD(p[1][1], mf.z, mf.w, Ee2.y, Ie2.y)
    }

    p[0][0] *= rd0; p[0][1] *= rd0;
    p[1][0] *= rd1; p[1][1] *= rd1;

    // ---- store: 2 rows x float2 per thread (8B-aligned: n even) ----
    #pragma unroll
    for (int i = 0; i < 2; ++i) {
        const int m = m0 + mi + i;
        if (m >= M) continue;
        const int n = n0 + ni;
        if (n + 2 <= N) {
            *reinterpret_cast<float2*>(&out[(size_t)m * N + n]) =
                make_float2(p[i][0], p[i][1]);
        } else {
            if (n < N)     out[(size_t)m * N + n]     = p[i][0];
            if (n + 1 < N) out[(size_t)m * N + n + 1] = p[i][1];
        }
    }
}

extern "C" void kernel_launch(void* const* d_in, const int* in_sizes, int n_in,
                              void* d_out, int out_size, void* d_ws, size_t ws_size,
                              hipStream_t stream) {
    const float* men = (const float*)d_in[0];
    const float* en  = (const float*)d_in[1];
    float* out = (float*)d_out;
    const int M = in_sizes[0] / 128;   // 256
    const int N = in_sizes[1] / 128;   // 20000
    dim3 grid((N + BN - 1) / BN, (M + BM - 1) / BM);
    ivr_kernel<<<grid, dim3(512), 0, stream>>>(men, en, out, M, N);
}

// Round 10
// 133.467 us; speedup vs baseline: 1.0317x; 1.0317x over previous
//
#include <hip/hip_runtime.h>

// out[m,n] = prod_d softplus(min(Zm,Ze)-max(zm,ze)) / softplus(Zm-zm)
//
// v10r = v10 resubmitted verbatim: round-9 bench failed with
// "MI355X container failed twice" (infra; no compile/correctness signal,
// no counters). Re-running the identical experiment to keep the A/B clean.
//
// v10 = v7 geometry VERBATIM (BM=BN=64, 512T, 2x4/thread, LDS 64KB,
// single-phase, register-rden) with the inner loop rewritten in j-PAIRED
// packed-fp32 form. v9's decisive result: occupancy 50% made dur WORSE ->
// the VALU issue port is the serialized resource; VALUBusy*dur = total
// issue cycles is the floor. Issue budget per FD at v7: 4 main ops (8cy)
// + v_log_f32 (~16cy) + ds/misc (~6cy) = 30cy. The log count is
// algorithmically irreducible; the reducible slice is main ops: gfx950
// VOP3P has v_pk_fma_f32 / v_pk_mul_f32 (no pk min), so the 1+u fma and
// the accumulate mul are done on j-pairs: 48 -> 44 cy per 2 FDs (-8%
// busy). Compiler never formed pk from scalar code (busy invariant
// v1..v8), so we hand it ext_vector_type(2) ops with operands already
// adjacent (Ee4.x/.y come from one ds_read_b128).
// Falsifier: busy time flat -> RA movs ate the gain -> practical floor
// reached, declare next round.
//
// Math per unit (identical numerics to v1..v9, absmax 5.6e-17):
//   u = min(Em,Ee)*min(Im,Ie) = e^{min(Zm,Ze)-max(zm,ze)};
//   p *= log2(1+u); ln2^64 cancels between numerator and denominator;
//   final scale by full-row 1/prod_d log2(1+e^{Zm-zm}).

#define BM 64
#define BN 64
#define DD 64

typedef float v2f __attribute__((ext_vector_type(2)));

// two fused-dim units (one j-pair): pk_fma for 1+u, 2x raw v_log, pk_mul acc
#define FDPAIR(P, EMS, IMS, EE0, EE1, IE0, IE1) { \
    v2f mE_, mI_; \
    mE_.x = fminf(EMS, EE0); mE_.y = fminf(EMS, EE1); \
    mI_.x = fminf(IMS, IE0); mI_.y = fminf(IMS, IE1); \
    const v2f w_ = __builtin_elementwise_fma(mE_, mI_, one2);   /* v_pk_fma_f32 */ \
    v2f lg_; \
    lg_.x = __builtin_amdgcn_logf(w_.x); \
    lg_.y = __builtin_amdgcn_logf(w_.y); \
    P = P * lg_;                                                /* v_pk_mul_f32 */ }

__global__ __launch_bounds__(512, 4)
void ivr_kernel(const float* __restrict__ men, const float* __restrict__ en,
                float* __restrict__ out, int M, int N) {
    __shared__ __align__(16) float2 sMen[DD][BM];  // (e^{Zm}, e^{-zm}) [d][m] 32 KB
    __shared__ __align__(16) float  sEe[DD][BN];   // e^{Ze}   [d][n]          16 KB
    __shared__ __align__(16) float  sIe[DD][BN];   // e^{-ze}                  16 KB

    const int tx = threadIdx.x;
    const int m0 = blockIdx.y * BM;
    const int n0 = blockIdx.x * BN;

    // ---- men staging + in-register row denominator (v7 verbatim) ----
    float rden;
    {
        const int ml  = tx >> 3;         // 0..63
        const int dcM = (tx & 7) * 8;    // this thread's 8 d's
        int mm = m0 + ml; if (mm >= M) mm = M - 1;
        const float* r = men + (size_t)mm * 128 + dcM;
        const float4 z0 = *reinterpret_cast<const float4*>(r);        // z (min)
        const float4 z1 = *reinterpret_cast<const float4*>(r + 4);
        const float4 Z0 = *reinterpret_cast<const float4*>(r + 64);   // Z (max)
        const float4 Z1 = *reinterpret_cast<const float4*>(r + 68);
        float Em, Im, prod;
#define MSTG(K, ZV, ZZ) { Em = __expf(ZZ); Im = __expf(-(ZV)); \
        sMen[dcM + (K)][ml] = make_float2(Em, Im); \
        prod *= __builtin_amdgcn_logf(__builtin_fmaf(Em, Im, 1.0f)); }
        Em = __expf(Z0.x); Im = __expf(-z0.x);
        sMen[dcM + 0][ml] = make_float2(Em, Im);
        prod = __builtin_amdgcn_logf(__builtin_fmaf(Em, Im, 1.0f));
        MSTG(1, z0.y, Z0.y) MSTG(2, z0.z, Z0.z) MSTG(3, z0.w, Z0.w)
        MSTG(4, z1.x, Z1.x) MSTG(5, z1.y, Z1.y) MSTG(6, z1.z, Z1.z) MSTG(7, z1.w, Z1.w)
#undef MSTG
        prod *= __shfl_xor(prod, 1);
        prod *= __shfl_xor(prod, 2);
        prod *= __shfl_xor(prod, 4);
        rden = 1.0f / prod;              // full-row 1/denominator
    }
    // ---- entity staging: lane -> row (conflict-free LDS writes, v7) ----
    {
        const int nl  = tx & 63;
        const int dcE = (tx >> 6) * 8;
        int nn = n0 + nl; if (nn >= N) nn = N - 1;
        const float* r = en + (size_t)nn * 128 + dcE;
        const float4 z0 = *reinterpret_cast<const float4*>(r);
        const float4 z1 = *reinterpret_cast<const float4*>(r + 4);
        const float4 Z0 = *reinterpret_cast<const float4*>(r + 64);
        const float4 Z1 = *reinterpret_cast<const float4*>(r + 68);
#define ESTG(K, ZV, ZZ) { sEe[dcE + (K)][nl] = __expf(ZZ); \
                          sIe[dcE + (K)][nl] = __expf(-(ZV)); }
        ESTG(0, z0.x, Z0.x) ESTG(1, z0.y, Z0.y) ESTG(2, z0.z, Z0.z) ESTG(3, z0.w, Z0.w)
        ESTG(4, z1.x, Z1.x) ESTG(5, z1.y, Z1.y) ESTG(6, z1.z, Z1.z) ESTG(7, z1.w, Z1.w)
#undef ESTG
    }
    __syncthreads();

    const int ni = (tx & 15) * 4;        // 16 n-groups of 4
    const int mi = (tx >> 4) * 2;        // 32 m-pairs

    const float oden = __shfl_xor(rden, 8);
    const int hib = (tx >> 3) & 1;
    const float rd0 = hib ? oden : rden;
    const float rd1 = hib ? rden : oden;

    const v2f one2 = {1.0f, 1.0f};
    // accumulators: (i, j-pair) -> v2f; components are independent outputs
    v2f p00 = one2, p01 = one2, p10 = one2, p11 = one2;

    // ---- compute: 8 FDs per d as 4 packed j-pairs ----
    #pragma unroll 8
    for (int d = 0; d < DD; ++d) {
        const float4 mf  = *reinterpret_cast<const float4*>(&sMen[d][mi]);  // Em0,Im0,Em1,Im1
        const float4 Ee4 = *reinterpret_cast<const float4*>(&sEe[d][ni]);
        const float4 Ie4 = *reinterpret_cast<const float4*>(&sIe[d][ni]);
        FDPAIR(p00, mf.x, mf.y, Ee4.x, Ee4.y, Ie4.x, Ie4.y)
        FDPAIR(p01, mf.x, mf.y, Ee4.z, Ee4.w, Ie4.z, Ie4.w)
        FDPAIR(p10, mf.z, mf.w, Ee4.x, Ee4.y, Ie4.x, Ie4.y)
        FDPAIR(p11, mf.z, mf.w, Ee4.z, Ee4.w, Ie4.z, Ie4.w)
    }

    p00 = p00 * rd0; p01 = p01 * rd0;
    p10 = p10 * rd1; p11 = p11 * rd1;

    // ---- store: 2 rows x float4 per thread ----
    {
        const int n = n0 + ni;
        const int m0r = m0 + mi;
        if (m0r < M) {
            float* o = out + (size_t)m0r * N + n;
            if (n + 4 <= N) {
                *reinterpret_cast<float4*>(o) = make_float4(p00.x, p00.y, p01.x, p01.y);
            } else {
                if (n < N)     o[0] = p00.x;
                if (n + 1 < N) o[1] = p00.y;
                if (n + 2 < N) o[2] = p01.x;
                if (n + 3 < N) o[3] = p01.y;
            }
        }
        if (m0r + 1 < M) {
            float* o = out + (size_t)(m0r + 1) * N + n;
            if (n + 4 <= N) {
                *reinterpret_cast<float4*>(o) = make_float4(p10.x, p10.y, p11.x, p11.y);
            } else {
                if (n < N)     o[0] = p10.x;
                if (n + 1 < N) o[1] = p10.y;
                if (n + 2 < N) o[2] = p11.x;
                if (n + 3 < N) o[3] = p11.y;
            }
        }
    }
}

extern "C" void kernel_launch(void* const* d_in, const int* in_sizes, int n_in,
                              void* d_out, int out_size, void* d_ws, size_t ws_size,
                              hipStream_t stream) {
    const float* men = (const float*)d_in[0];
    const float* en  = (const float*)d_in[1];
    float* out = (float*)d_out;
    const int M = in_sizes[0] / 128;   // 256
    const int N = in_sizes[1] / 128;   // 20000
    dim3 grid((N + BN - 1) / BN, (M + BM - 1) / BM);
    ivr_kernel<<<grid, dim3(512), 0, stream>>>(men, en, out, M, N);
}